// Round 10
// baseline (79.790 us; speedup 1.0000x reference)
//
#include <hip/hip_runtime.h>

#define GAMMA 0.1f

constexpr int MTOT = 65536;
constexpr int NTOT = 1024;
constexpr int KDIM = 64;
constexpr int BM = 128;     // x rows per m-tile (DOUBLED vs R8)
constexpr int BN = 128;     // centers per block
constexpr int NTIL = 8;     // m-tiles per block (HALVED vs R8); grid = 8*64 = 512

using frag_ab = __attribute__((ext_vector_type(8))) short;  // 8 bf16 (4 VGPRs)
using bf16x4  = __attribute__((ext_vector_type(4))) short;  // 4 bf16 (8 B)
using f32x4   = __attribute__((ext_vector_type(4))) float;  // 4 f32 acc

// f32 -> bf16 round-to-nearest-even; 'back' is the rounded value as f32.
__device__ __forceinline__ ushort bf16_rne(float v, float& back) {
  unsigned u = __float_as_uint(v);
  unsigned r = (u + 0x7FFFu + ((u >> 16) & 1u)) >> 16;
  back = __uint_as_float(r << 16);
  return (ushort)r;
}

__global__ __launch_bounds__(512, 4)
void rbf_kernel(const float* __restrict__ x,
                const float* __restrict__ centers,
                float* __restrict__ out) {
  __shared__ ushort sChi[BN * KDIM];   // 16 KB (XOR-swizzled)
  __shared__ ushort sClo[BN * KDIM];   // 16 KB
  __shared__ float  sCsq[BN];
  __shared__ ushort sXhi[BM * KDIM];   // 16 KB (XOR-swizzled, rewritten per tile)
  __shared__ ushort sXlo[BM * KDIM];   // 16 KB
  __shared__ float  sXsq[BM];
  // ~64.5 KB -> 2 blocks/CU (16 waves)

  const int tid = threadIdx.x;
  const int nt = blockIdx.x & 7;    // R1/R8 known-good mapping
  const int mg = blockIdx.x >> 3;   // 0..63; block handles mt = mg + 64*j

  // ---- prologue: issue tile-0 x loads (flat float4: 1KB/wave/inst, coalesced) ----
  float4 rx[4];
  {
    const float4* p = reinterpret_cast<const float4*>(x + (size_t)mg * BM * KDIM);
    #pragma unroll
    for (int i = 0; i < 4; ++i) rx[i] = p[tid + 512 * i];
  }

  // ---- stage centers tile once (R8 code, verified): f32 -> bf16 hi/lo + csq ----
  #pragma unroll
  for (int pass = 0; pass < 2; ++pass) {
    const int idx = pass * 4096 + tid * 8;
    const int row = idx >> 6;               // 0..127
    const int s = tid & 7;
    const float4* p = reinterpret_cast<const float4*>(
        centers + (size_t)nt * BN * KDIM + idx);
    float4 v0 = p[0], v1 = p[1];
    float v[8] = {v0.x, v0.y, v0.z, v0.w, v1.x, v1.y, v1.z, v1.w};
    frag_ab hv, lv;
    float ss = 0.0f;
    #pragma unroll
    for (int i = 0; i < 8; ++i) {
      float back;
      ushort hb = bf16_rne(v[i], back);
      float b2;
      ushort lb = bf16_rne(v[i] - back, b2);
      (void)b2;
      ss += v[i] * v[i];
      hv[i] = (short)hb;
      lv[i] = (short)lb;
    }
    ss += __shfl_xor(ss, 1);
    ss += __shfl_xor(ss, 2);
    ss += __shfl_xor(ss, 4);
    if (s == 0) sCsq[row] = ss;
    const int slot = s ^ (row & 7);
    *reinterpret_cast<frag_ab*>(sChi + row * 64 + slot * 8) = hv;
    *reinterpret_cast<frag_ab*>(sClo + row * 64 + slot * 8) = lv;
  }
  __syncthreads();   // centers staged

  const int lane = tid & 63;
  const int wave = tid >> 6;        // 0..7
  const int wm = wave & 3;          // m-quarter: 32 x-rows
  const int wn = wave >> 2;         // n-half: 64 centers
  const int l = lane & 15;
  const int g = lane >> 4;          // k-group 0..3

  // hoist csq float4s (D-layout: lane (g,l) owns centers nf*16+g*4+{0..3})
  float4 csq4[4];
  #pragma unroll
  for (int nf = 0; nf < 4; ++nf)
    csq4[nf] = *reinterpret_cast<const float4*>(&sCsq[wn * 64 + nf * 16 + g * 4]);

  const int q16 = tid >> 4;         // row-group 0..31 (flat-load ownership)
  const int f15 = tid & 15;         // float4-idx within row
  const int ncol0 = nt * BN + wn * 64;

  // ================= persistent m-loop: 8 tiles, 2 barriers each =================
  #pragma unroll 1
  for (int j = 0; j < NTIL; ++j) {
    const int mt = mg + 64 * j;     // 128-row tiles, interleaved GPU-wide

    // ---- A: convert rx (tile j) -> bf16 hi/lo LDS + row norms ----
    // Thread's rx[i] is float4 #(tid + 512 i) = row (q16 + 32 i), chunk f15.
    float ssr[4];
    #pragma unroll
    for (int i = 0; i < 4; ++i) {
      const int row = q16 + 32 * i;
      const int s = f15 >> 1;        // 8-elem chunk
      const int c = f15 & 1;         // half of chunk
      const float vv[4] = {rx[i].x, rx[i].y, rx[i].z, rx[i].w};
      bf16x4 hv, lv;
      float ss = 0.0f;
      #pragma unroll
      for (int e = 0; e < 4; ++e) {
        float back;
        ushort hb = bf16_rne(vv[e], back);
        float b2;
        ushort lb = bf16_rne(vv[e] - back, b2);
        (void)b2;
        ss += vv[e] * vv[e];
        hv[e] = (short)hb;
        lv[e] = (short)lb;
      }
      ssr[i] = ss;
      const int slot = s ^ (row & 7);   // same swizzle family as R1/R8 (verified)
      *reinterpret_cast<bf16x4*>(sXhi + row * 64 + slot * 8 + c * 4) = hv;
      *reinterpret_cast<bf16x4*>(sXlo + row * 64 + slot * 8 + c * 4) = lv;
    }
    // row sums: 16 lanes share a row-group (xor 1,2,4,8 stays in-group)
    #pragma unroll
    for (int i = 0; i < 4; ++i) {
      ssr[i] += __shfl_xor(ssr[i], 1);
      ssr[i] += __shfl_xor(ssr[i], 2);
      ssr[i] += __shfl_xor(ssr[i], 4);
      ssr[i] += __shfl_xor(ssr[i], 8);
    }
    if (f15 == 0) {
      #pragma unroll
      for (int i = 0; i < 4; ++i) sXsq[q16 + 32 * i] = ssr[i];
    }
    __syncthreads();   // x tile j visible

    // ---- issue tile j+1 loads now; they fly under frag/MFMA/epilogue (T14) ----
    if (j + 1 < NTIL) {
      const float4* p = reinterpret_cast<const float4*>(
          x + (size_t)(mg + 64 * (j + 1)) * BM * KDIM);
      #pragma unroll
      for (int i = 0; i < 4; ++i) rx[i] = p[tid + 512 * i];
    }

    // ---- x fragments (conflict-free b128 via swizzled slots) ----
    frag_ab xh[2][2], xl[2][2];     // [ks][mf]
    float xs[2];
    #pragma unroll
    for (int mf = 0; mf < 2; ++mf) {
      const int row = wm * 32 + mf * 16 + l;
      xs[mf] = sXsq[row];
      #pragma unroll
      for (int ks = 0; ks < 2; ++ks) {
        const int slot = (ks * 4 + g) ^ (l & 7);
        xh[ks][mf] = *reinterpret_cast<const frag_ab*>(sXhi + row * 64 + slot * 8);
        xl[ks][mf] = *reinterpret_cast<const frag_ab*>(sXlo + row * 64 + slot * 8);
      }
    }

    // ---- MFMA: cross = ch*xh + ch*xl + cl*xh (A=centers, B=x; R8-verified) ----
    f32x4 acc[4][2] = {};           // [nf][mf]
    #pragma unroll
    for (int ks = 0; ks < 2; ++ks) {
      const int slot = (ks * 4 + g) ^ (l & 7);
      #pragma unroll
      for (int nf = 0; nf < 4; ++nf) {
        const int crow = wn * 64 + nf * 16 + l;
        const frag_ab ch = *reinterpret_cast<const frag_ab*>(sChi + crow * 64 + slot * 8);
        const frag_ab cl = *reinterpret_cast<const frag_ab*>(sClo + crow * 64 + slot * 8);
        #pragma unroll
        for (int mf = 0; mf < 2; ++mf) {
          acc[nf][mf] = __builtin_amdgcn_mfma_f32_16x16x32_bf16(ch, xh[ks][mf], acc[nf][mf], 0, 0, 0);
          acc[nf][mf] = __builtin_amdgcn_mfma_f32_16x16x32_bf16(ch, xl[ks][mf], acc[nf][mf], 0, 0, 0);
          acc[nf][mf] = __builtin_amdgcn_mfma_f32_16x16x32_bf16(cl, xh[ks][mf], acc[nf][mf], 0, 0, 0);
        }
      }
    }

    // ---- epilogue: lane-local finish, float4 stores along n (R8-verified) ----
    #pragma unroll
    for (int mf = 0; mf < 2; ++mf) {
      const size_t rowg = (size_t)mt * BM + wm * 32 + mf * 16 + l;
      float* orow = out + rowg * (size_t)NTOT + ncol0;
      #pragma unroll
      for (int nf = 0; nf < 4; ++nf) {
        const f32x4 a = acc[nf][mf];
        const float4 cs = csq4[nf];
        float4 o;
        o.x = __expf(-GAMMA * fmaxf(xs[mf] + cs.x - 2.0f * a[0], 0.0f));
        o.y = __expf(-GAMMA * fmaxf(xs[mf] + cs.y - 2.0f * a[1], 0.0f));
        o.z = __expf(-GAMMA * fmaxf(xs[mf] + cs.z - 2.0f * a[2], 0.0f));
        o.w = __expf(-GAMMA * fmaxf(xs[mf] + cs.w - 2.0f * a[3], 0.0f));
        *reinterpret_cast<float4*>(orow + nf * 16 + g * 4) = o;
      }
    }

    __syncthreads();   // LDS tile j consumption done -> safe to overwrite in j+1
  }
}

extern "C" void kernel_launch(void* const* d_in, const int* in_sizes, int n_in,
                              void* d_out, int out_size, void* d_ws, size_t ws_size,
                              hipStream_t stream) {
  (void)in_sizes; (void)n_in; (void)d_ws; (void)ws_size; (void)out_size;
  const float* x       = (const float*)d_in[0];
  const float* centers = (const float*)d_in[1];
  float* out = (float*)d_out;
  rbf_kernel<<<512, 512, 0, stream>>>(x, centers, out);
}

// Round 11
// 67.009 us; speedup vs baseline: 1.1907x; 1.1907x over previous
//
#include <hip/hip_runtime.h>

#define GAMMA 0.1f

constexpr int MTOT = 65536;
constexpr int NTOT = 1024;
constexpr int KDIM = 64;
constexpr int BM   = 128;         // x rows per block; grid = 512 = exactly 2/CU
constexpr int BNT  = 64;          // centers per tile
constexpr int NIT  = NTOT / BNT;  // 16 center-tiles

using frag_ab = __attribute__((ext_vector_type(8))) short;  // 8 bf16 (4 VGPRs)
using bf16x4  = __attribute__((ext_vector_type(4))) short;  // 4 bf16 (8 B)
using f32x4   = __attribute__((ext_vector_type(4))) float;  // 4 f32 acc

typedef __attribute__((address_space(1))) const unsigned int gu32;
typedef __attribute__((address_space(3))) unsigned int lu32;

// ---------------- workspace layout (bytes) ----------------
constexpr size_t WS_CHI = 0;            // 1024*64*2 = 131072 (pre-swizzled bf16 hi)
constexpr size_t WS_CLO = 131072;       // 131072 (bf16 lo)
constexpr size_t WS_CSQ = 262144;       // 1024*4 (norms)
// ws_size proven >= 17 MB in R2; we need 266 KB.

// f32 -> bf16 round-to-nearest-even; 'back' is the rounded value as f32.
__device__ __forceinline__ ushort bf16_rne(float v, float& back) {
  unsigned u = __float_as_uint(v);
  unsigned r = (u + 0x7FFFu + ((u >> 16) & 1u)) >> 16;
  back = __uint_as_float(r << 16);
  return (ushort)r;
}

// ======== kernel 1 (R9-verified): centers f32 -> bf16 hi/lo pre-swizzled + csq ========
__global__ __launch_bounds__(256)
void cen_convert_kernel(const float* __restrict__ centers,
                        ushort* __restrict__ hi, ushort* __restrict__ lo,
                        float* __restrict__ sq) {
  const int c = blockIdx.x * 256 + threadIdx.x;
  const int row = c >> 3;
  const int s = c & 7;
  const float4* p = reinterpret_cast<const float4*>(centers + (size_t)row * KDIM + s * 8);
  float4 v0 = p[0], v1 = p[1];
  float v[8] = {v0.x, v0.y, v0.z, v0.w, v1.x, v1.y, v1.z, v1.w};
  frag_ab hv, lv;
  float ss = 0.0f;
  #pragma unroll
  for (int i = 0; i < 8; ++i) {
    float back;
    ushort hb = bf16_rne(v[i], back);
    float b2;
    ushort lb = bf16_rne(v[i] - back, b2);
    (void)b2;
    ss += v[i] * v[i];
    hv[i] = (short)hb;
    lv[i] = (short)lb;
  }
  ss += __shfl_xor(ss, 1);
  ss += __shfl_xor(ss, 2);
  ss += __shfl_xor(ss, 4);
  if (s == 0) sq[row] = ss;
  const int slot = s ^ (row & 7);  // bake LDS bank swizzle into the ws layout
  *reinterpret_cast<frag_ab*>(hi + (size_t)row * KDIM + slot * 8) = hv;
  *reinterpret_cast<frag_ab*>(lo + (size_t)row * KDIM + slot * 8) = lv;
}

// ======== kernel 2: x-resident blocks, centers looped with counted-vmcnt pipeline ========
// Block = 128 x-rows (staged once). 16 center-tiles DMA'd double-buffered from
// L2-resident ws. Raw s_barrier + s_waitcnt vmcnt(6): prefetch SURVIVES the
// barrier (no vmcnt(0) drain in the loop). A=centers, B=x (R8/R9-verified) ->
// lane-local float4 epilogue; full 128B lines per iteration.
__global__ __launch_bounds__(512, 4)
void rbf_main_kernel(const float* __restrict__ x,
                     const ushort* __restrict__ chi,
                     const ushort* __restrict__ clo,
                     const float* __restrict__ csq,
                     float* __restrict__ out) {
  __shared__ ushort sXhi[BM * KDIM];     // 16 KB (XOR-swizzled)
  __shared__ ushort sXlo[BM * KDIM];     // 16 KB
  __shared__ float  sXsq[BM];            // 512 B
  __shared__ ushort sCen[2][8192];       // dbuf x [hi 8KB | lo 8KB] = 32 KB
  __shared__ float  sCsqAll[NTOT];       // 4 KB
  // total ~68.5 KB -> 2 blocks/CU

  const int tid = threadIdx.x;
  const int mb  = blockIdx.x;            // 0..511

  // DMA one 64-center tile (hi+lo, 16 KB) into buffer b. 2 vmcnt ops/thread.
  auto issue_cen = [&](int nt, int b) {
    const char* sH = reinterpret_cast<const char*>(chi) + (size_t)nt * 8192;
    const char* sL = reinterpret_cast<const char*>(clo) + (size_t)nt * 8192;
    char* d = reinterpret_cast<char*>(&sCen[b][0]);
    __builtin_amdgcn_global_load_lds((gu32*)(sH + (size_t)tid * 16),
                                     (lu32*)(d + (size_t)tid * 16), 16, 0, 0);
    __builtin_amdgcn_global_load_lds((gu32*)(sL + (size_t)tid * 16),
                                     (lu32*)(d + 8192 + (size_t)tid * 16), 16, 0, 0);
  };

  // ---- prologue: issue tiles 0,1 + csq DMA; stage x; one full drain ----
  issue_cen(0, 0);
  {
    const int c = tid & 255;   // wave-uniform op count (all waves issue 1)
    __builtin_amdgcn_global_load_lds(
        (gu32*)(reinterpret_cast<const char*>(csq) + (size_t)c * 16),
        (lu32*)(reinterpret_cast<char*>(sCsqAll) + (size_t)c * 16), 16, 0, 0);
  }
  issue_cen(1, 1);

  // stage x-tile once: 2048 float4s; thread handles 4, rows grouped per 16 lanes
  #pragma unroll
  for (int p = 0; p < 4; ++p) {
    const int c = p * 512 + tid;          // float4 id 0..2047
    const int row = c >> 4;               // 0..127
    const int f15 = c & 15;
    const int s = f15 >> 1;               // 8-elem chunk
    const int half = f15 & 1;
    const float4 v4 = reinterpret_cast<const float4*>(x + (size_t)mb * BM * KDIM)[c];
    const float vv[4] = {v4.x, v4.y, v4.z, v4.w};
    bf16x4 hv, lv;
    float ss = 0.0f;
    #pragma unroll
    for (int e = 0; e < 4; ++e) {
      float back;
      ushort hb = bf16_rne(vv[e], back);
      float b2;
      ushort lb = bf16_rne(vv[e] - back, b2);
      (void)b2;
      ss += vv[e] * vv[e];
      hv[e] = (short)hb;
      lv[e] = (short)lb;
    }
    ss += __shfl_xor(ss, 1);
    ss += __shfl_xor(ss, 2);
    ss += __shfl_xor(ss, 4);
    ss += __shfl_xor(ss, 8);
    if (f15 == 0) sXsq[row] = ss;
    const int slot = s ^ (row & 7);       // R1-family swizzle (verified)
    *reinterpret_cast<bf16x4*>(sXhi + row * 64 + slot * 8 + half * 4) = hv;
    *reinterpret_cast<bf16x4*>(sXlo + row * 64 + slot * 8 + half * 4) = lv;
  }
  __syncthreads();   // one-time full drain: x staged, tiles 0,1 + csq landed

  const int lane = tid & 63;
  const int wave = tid >> 6;      // 0..7
  const int wm = wave & 3;        // m-quarter: 32 x-rows
  const int wn = wave >> 2;       // n-half of tile: 32 centers
  const int l = lane & 15;
  const int g = lane >> 4;        // k-group 0..3

  // ---- hoist x fragments + norms (invariant across all center-tiles) ----
  frag_ab xh[2][2], xl[2][2];     // [ks][mf]
  float xs[2];
  #pragma unroll
  for (int mf = 0; mf < 2; ++mf) {
    const int row = wm * 32 + mf * 16 + l;
    xs[mf] = sXsq[row];
    #pragma unroll
    for (int ks = 0; ks < 2; ++ks) {
      const int slot = (ks * 4 + g) ^ (l & 7);
      xh[ks][mf] = *reinterpret_cast<const frag_ab*>(sXhi + row * 64 + slot * 8);
      xl[ks][mf] = *reinterpret_cast<const frag_ab*>(sXlo + row * 64 + slot * 8);
    }
  }

  // ================= center-tile loop: counted-vmcnt pipeline =================
  #pragma unroll 1
  for (int j = 0; j < NIT; ++j) {
    const int b = j & 1;

    // ---- MFMA: cross = ch*xh + ch*xl + cl*xh (lo*lo dropped, ~1e-6) ----
    f32x4 acc[2][2] = {};          // [nf][mf]
    #pragma unroll
    for (int ks = 0; ks < 2; ++ks) {
      const int slot = (ks * 4 + g) ^ (l & 7);
      #pragma unroll
      for (int nf = 0; nf < 2; ++nf) {
        const int rr = wn * 32 + nf * 16 + l;
        const frag_ab ch = *reinterpret_cast<const frag_ab*>(&sCen[b][rr * 64 + slot * 8]);
        const frag_ab cl = *reinterpret_cast<const frag_ab*>(&sCen[b][4096 + rr * 64 + slot * 8]);
        #pragma unroll
        for (int mf = 0; mf < 2; ++mf) {
          acc[nf][mf] = __builtin_amdgcn_mfma_f32_16x16x32_bf16(ch, xh[ks][mf], acc[nf][mf], 0, 0, 0);
          acc[nf][mf] = __builtin_amdgcn_mfma_f32_16x16x32_bf16(ch, xl[ks][mf], acc[nf][mf], 0, 0, 0);
          acc[nf][mf] = __builtin_amdgcn_mfma_f32_16x16x32_bf16(cl, xh[ks][mf], acc[nf][mf], 0, 0, 0);
        }
      }
    }

    // ---- epilogue: lane-local finish, float4 stores (full lines per iter) ----
    const int ncol = j * 64 + wn * 32;
    #pragma unroll
    for (int nf = 0; nf < 2; ++nf) {
      const float4 cs = *reinterpret_cast<const float4*>(&sCsqAll[ncol + nf * 16 + g * 4]);
      #pragma unroll
      for (int mf = 0; mf < 2; ++mf) {
        const size_t rowg = (size_t)mb * BM + wm * 32 + mf * 16 + l;
        const f32x4 a = acc[nf][mf];
        float4 o;
        o.x = __expf(-GAMMA * fmaxf(xs[mf] + cs.x - 2.0f * a[0], 0.0f));
        o.y = __expf(-GAMMA * fmaxf(xs[mf] + cs.y - 2.0f * a[1], 0.0f));
        o.z = __expf(-GAMMA * fmaxf(xs[mf] + cs.z - 2.0f * a[2], 0.0f));
        o.w = __expf(-GAMMA * fmaxf(xs[mf] + cs.w - 2.0f * a[3], 0.0f));
        *reinterpret_cast<float4*>(out + rowg * (size_t)NTOT + ncol + nf * 16 + g * 4) = o;
      }
    }

    if (j + 1 < NIT) {
      // reads of sCen[b] done (lgkm drained cheaply: results already consumed)
      asm volatile("s_waitcnt lgkmcnt(0)" ::: "memory");
      __builtin_amdgcn_s_barrier();            // all waves done reading buf b
      if (j + 2 < NIT) {
        issue_cen(j + 2, b);                   // overwrite buf b (safe now)
        // retire D(j+1): newest-6 = 4 stores + 2 new loads stay in flight
        asm volatile("s_waitcnt vmcnt(6)" ::: "memory");
      } else {
        // no new issue: D(j+1) guaranteed by leaving only the 4 stores
        asm volatile("s_waitcnt vmcnt(4)" ::: "memory");
      }
      __builtin_amdgcn_s_barrier();            // buf (j+1)&1 readable by ALL waves
      __builtin_amdgcn_sched_barrier(0);       // no ds_read hoisting above this
    }
  }
}

extern "C" void kernel_launch(void* const* d_in, const int* in_sizes, int n_in,
                              void* d_out, int out_size, void* d_ws, size_t ws_size,
                              hipStream_t stream) {
  (void)in_sizes; (void)n_in; (void)out_size; (void)ws_size;
  const float* x       = (const float*)d_in[0];
  const float* centers = (const float*)d_in[1];
  float* out = (float*)d_out;

  char* ws = (char*)d_ws;
  ushort* chi = (ushort*)(ws + WS_CHI);
  ushort* clo = (ushort*)(ws + WS_CLO);
  float*  csq = (float*)(ws + WS_CSQ);

  cen_convert_kernel<<<32, 256, 0, stream>>>(centers, chi, clo, csq);
  rbf_main_kernel<<<MTOT / BM, 512, 0, stream>>>(x, chi, clo, csq, out);
}

// Round 12
// 60.310 us; speedup vs baseline: 1.3230x; 1.1111x over previous
//
#include <hip/hip_runtime.h>

#define GAMMA 0.1f

constexpr int MTOT = 65536;
constexpr int NTOT = 1024;
constexpr int KDIM = 64;
constexpr int RPB  = 256;        // rows per block; grid = 256 = exactly 1 block/CU
constexpr int SUB  = 64;         // rows per sub-tile
constexpr int NSUB = RPB / SUB;  // 4 iterations

using f16x8 = __attribute__((ext_vector_type(8))) _Float16;  // MFMA A/B frag
using f16x4 = __attribute__((ext_vector_type(4))) _Float16;  // 8-B LDS store
using f32x4 = __attribute__((ext_vector_type(4))) float;     // MFMA C/D

typedef __attribute__((address_space(1))) const unsigned int gu32;
typedef __attribute__((address_space(3))) unsigned int lu32;

// ---------------- workspace layout (bytes) ----------------
constexpr size_t WS_CEN = 0;        // 1024*64 fp16 = 131072 (pre-swizzled)
constexpr size_t WS_CSQ = 131072;   // 1024 f32 norms = 4096
// ws_size proven >= 17 MB in R2; we need 135 KB.

// ======== kernel 1: centers f32 -> fp16 (pre-swizzled) + csq ========
// Thread c: row = c>>3 (0..1023), 16B slot s = c&7. Swizzle slot^(row&7) baked
// into the ws layout so kernel 2's linear DMA yields conflict-free frag reads.
__global__ __launch_bounds__(256)
void cen_convert_kernel(const float* __restrict__ centers,
                        _Float16* __restrict__ cen,
                        float* __restrict__ sq) {
  const int c = blockIdx.x * 256 + threadIdx.x;
  const int row = c >> 3;
  const int s = c & 7;
  const float4* p = reinterpret_cast<const float4*>(centers + (size_t)row * KDIM + s * 8);
  float4 v0 = p[0], v1 = p[1];
  const float v[8] = {v0.x, v0.y, v0.z, v0.w, v1.x, v1.y, v1.z, v1.w};
  f16x8 hv;
  float ss = 0.0f;
  #pragma unroll
  for (int i = 0; i < 8; ++i) {
    hv[i] = (_Float16)v[i];          // RNE
    ss += v[i] * v[i];               // norms from exact f32
  }
  ss += __shfl_xor(ss, 1);
  ss += __shfl_xor(ss, 2);
  ss += __shfl_xor(ss, 4);
  if (s == 0) sq[row] = ss;
  const int slot = s ^ (row & 7);
  *reinterpret_cast<f16x8*>(cen + (size_t)row * KDIM + slot * 8) = hv;
}

// ======== kernel 2: ALL 1024 centers LDS-resident; block writes full rows ========
// 1 block/CU (148.5 KB LDS), 1024 threads = 16 waves. Per iteration the block
// computes 64 rows x ALL 1024 cols and stores 256 KB CONTIGUOUS (fill-kernel
// write pattern -> DRAM page locality). 4 iterations, 1 raw barrier each, no
// vmcnt(0) drains (x loads issued before stores -> compiler emits counted wait).
__global__ __launch_bounds__(1024, 4)
void rbf_main_kernel(const float* __restrict__ x,
                     const _Float16* __restrict__ cen,
                     const float* __restrict__ csq,
                     float* __restrict__ out) {
  __shared__ _Float16 sCen[NTOT * KDIM];      // 128 KB, staged once, read-only
  __shared__ _Float16 sX[2][SUB * KDIM];      // 16 KB dbuf (XOR-swizzled)
  __shared__ float    sCsq[NTOT];             // 4 KB
  __shared__ float    sXsq[2][SUB];           // 512 B

  const int tid = threadIdx.x;
  const int mb = blockIdx.x;                  // 0..255

  const float4* xsrc = reinterpret_cast<const float4*>(x + (size_t)mb * RPB * KDIM);

  // x sub-tile convert: thread owns float4 #tid -> row tid>>4, 16B-slot pair
  auto convert_x = [&](float4 v4, int buf) {
    const int row = tid >> 4;                 // 0..63
    const int f15 = tid & 15;
    const int s = f15 >> 1;
    const int half = f15 & 1;
    const float vv[4] = {v4.x, v4.y, v4.z, v4.w};
    f16x4 hv;
    float ss = 0.0f;
    #pragma unroll
    for (int e = 0; e < 4; ++e) {
      hv[e] = (_Float16)vv[e];
      ss += vv[e] * vv[e];
    }
    ss += __shfl_xor(ss, 1);
    ss += __shfl_xor(ss, 2);
    ss += __shfl_xor(ss, 4);
    ss += __shfl_xor(ss, 8);
    if (f15 == 0) sXsq[buf][row] = ss;
    const int slot = s ^ (row & 7);
    *reinterpret_cast<f16x4*>(&sX[buf][row * KDIM + slot * 8 + half * 4]) = hv;
  };

  // ---- prologue ----
  float4 rx = xsrc[tid];                      // tile 0 (issued FIRST: oldest vmcnt)
  {                                           // centers DMA: 8192 chunks, linear
    const char* src = reinterpret_cast<const char*>(cen);
    char* dst = reinterpret_cast<char*>(sCen);
    #pragma unroll
    for (int p = 0; p < 8; ++p) {
      const int q = p * 1024 + tid;
      __builtin_amdgcn_global_load_lds((gu32*)(src + (size_t)q * 16),
                                       (lu32*)(dst + (size_t)q * 16), 16, 0, 0);
    }
  }
  if (tid < 256) {                            // csq DMA (waves 0..3, uniform base)
    __builtin_amdgcn_global_load_lds(
        (gu32*)(reinterpret_cast<const char*>(csq) + (size_t)tid * 16),
        (lu32*)(reinterpret_cast<char*>(sCsq) + (size_t)tid * 16), 16, 0, 0);
  }
  convert_x(rx, 0);                           // compiler: vmcnt(9) for rx
  rx = xsrc[1024 + tid];                      // tile 1 in flight
  asm volatile("s_waitcnt vmcnt(1)" ::: "memory");   // retire cen+csq DMA, keep rx
  asm volatile("s_waitcnt lgkmcnt(0)" ::: "memory");
  __builtin_amdgcn_s_barrier();
  __builtin_amdgcn_sched_barrier(0);

  const int lane = tid & 63;
  const int wave = tid >> 6;                  // 0..15
  const int wm = wave & 3;                    // 16-row group within sub-tile
  const int wn = wave >> 2;                   // 256-col group
  const int l = lane & 15;
  const int g = lane >> 4;                    // k-group 0..3

  // ================= 4 iterations: 64 rows x 1024 cols each =================
  #pragma unroll 1
  for (int jt = 0; jt < NSUB; ++jt) {
    const int b = jt & 1;

    // stage next x sub-tile (dbuf -> no barrier needed before writes)
    if (jt + 1 < NSUB) convert_x(rx, b ^ 1);            // waits vmcnt(16): 16 stores newer
    if (jt + 2 < NSUB) rx = xsrc[(jt + 2) * 1024 + tid]; // issued BEFORE this iter's stores

    // x fragments (B-operand): lane l <-> x-row, chunk g
    const int xrow = wm * 16 + l;
    f16x8 xh[2];
    #pragma unroll
    for (int ks = 0; ks < 2; ++ks) {
      const int slot = (ks * 4 + g) ^ (l & 7);
      xh[ks] = *reinterpret_cast<const f16x8*>(&sX[b][xrow * KDIM + slot * 8]);
    }
    const float xs = sXsq[b][xrow];

    // MFMA: A=centers (lane l <-> center row), 16 nf x 2 ks, single fp16 term
    f32x4 acc[16] = {};
    #pragma unroll
    for (int ks = 0; ks < 2; ++ks) {
      const int slot = (ks * 4 + g) ^ (l & 7);
      #pragma unroll
      for (int nf = 0; nf < 16; ++nf) {
        const int crow = wn * 256 + nf * 16 + l;
        const f16x8 ch = *reinterpret_cast<const f16x8*>(&sCen[crow * KDIM + slot * 8]);
        acc[nf] = __builtin_amdgcn_mfma_f32_16x16x32_f16(ch, xh[ks], acc[nf], 0, 0, 0);
      }
    }

    // epilogue: lane (g,l) owns centers nf*16+g*4+{0..3} at x-row l -> float4
    const size_t rowg = (size_t)mb * RPB + jt * SUB + wm * 16 + l;
    float* orow = out + rowg * (size_t)NTOT + wn * 256;
    #pragma unroll
    for (int nf = 0; nf < 16; ++nf) {
      const float4 cs = *reinterpret_cast<const float4*>(&sCsq[wn * 256 + nf * 16 + g * 4]);
      const f32x4 a = acc[nf];
      float4 o;
      o.x = __expf(-GAMMA * fmaxf(xs + cs.x - 2.0f * a[0], 0.0f));
      o.y = __expf(-GAMMA * fmaxf(xs + cs.y - 2.0f * a[1], 0.0f));
      o.z = __expf(-GAMMA * fmaxf(xs + cs.z - 2.0f * a[2], 0.0f));
      o.w = __expf(-GAMMA * fmaxf(xs + cs.w - 2.0f * a[3], 0.0f));
      *reinterpret_cast<float4*>(orow + nf * 16 + g * 4) = o;
    }

    if (jt + 1 < NSUB) {
      asm volatile("s_waitcnt lgkmcnt(0)" ::: "memory");  // ds_writes visible
      __builtin_amdgcn_s_barrier();                       // raw: stores stay in flight
      __builtin_amdgcn_sched_barrier(0);                  // no hoisting across
    }
  }
}

extern "C" void kernel_launch(void* const* d_in, const int* in_sizes, int n_in,
                              void* d_out, int out_size, void* d_ws, size_t ws_size,
                              hipStream_t stream) {
  (void)in_sizes; (void)n_in; (void)out_size; (void)ws_size;
  const float* x       = (const float*)d_in[0];
  const float* centers = (const float*)d_in[1];
  float* out = (float*)d_out;

  char* ws = (char*)d_ws;
  _Float16* cen = (_Float16*)(ws + WS_CEN);
  float*    csq = (float*)(ws + WS_CSQ);

  cen_convert_kernel<<<32, 256, 0, stream>>>(centers, cen, csq);
  rbf_main_kernel<<<MTOT / RPB, 1024, 0, stream>>>(x, cen, csq, out);
}

// Round 13
// 59.390 us; speedup vs baseline: 1.3435x; 1.0155x over previous
//
#include <hip/hip_runtime.h>

#define GAMMA 0.1f

constexpr int MTOT = 65536;
constexpr int NTOT = 1024;
constexpr int KDIM = 64;
constexpr int RPB  = 256;        // rows per block; grid = 256 = exactly 1 block/CU
constexpr int SUB  = 32;         // rows per sub-tile
constexpr int NSUB = RPB / SUB;  // 8 iterations

using f16x8 = __attribute__((ext_vector_type(8))) _Float16;  // MFMA A/B frag
using f16x4 = __attribute__((ext_vector_type(4))) _Float16;  // 8-B LDS store
using f32x4 = __attribute__((ext_vector_type(4))) float;     // MFMA C/D

// Single fused kernel. All 1024 centers LDS-resident as fp16 (XOR-swizzled),
// converted in-block from f32 (L3-resident; no pre-pass, no workspace).
// Per iteration: 32 x-rows x ALL 1024 cols -> 128 KB contiguous stores
// (fill-kernel write pattern). 8 iterations, 1 raw barrier each, no vmcnt(0)
// drains in the loop. A=centers, B=x (R8/R12-verified) -> lane-local float4.
__global__ __launch_bounds__(1024, 4)
void rbf_fused_kernel(const float* __restrict__ x,
                      const float* __restrict__ centers,
                      float* __restrict__ out) {
  __shared__ _Float16 sCen[NTOT * KDIM];      // 128 KB, staged once, read-only
  __shared__ _Float16 sX[2][SUB * KDIM];      // 8 KB dbuf (XOR-swizzled)
  __shared__ float    sCsq[NTOT];             // 4 KB
  __shared__ float    sXsq[2][SUB];           // 256 B
  // total ~140.3 KB -> 1 block/CU (16 waves)

  const int tid = threadIdx.x;
  const int mb = blockIdx.x;                  // 0..255

  const float4* xsrc = reinterpret_cast<const float4*>(x + (size_t)mb * RPB * KDIM);

  // x sub-tile convert (threads 0..511): float4 #tid -> row tid>>4, slot-half
  auto convert_x = [&](float4 v4, int buf) {
    const int row = tid >> 4;                 // 0..31
    const int f15 = tid & 15;
    const int s = f15 >> 1;
    const int half = f15 & 1;
    const float vv[4] = {v4.x, v4.y, v4.z, v4.w};
    f16x4 hv;
    float ss = 0.0f;
    #pragma unroll
    for (int e = 0; e < 4; ++e) {
      hv[e] = (_Float16)vv[e];
      ss += vv[e] * vv[e];
    }
    ss += __shfl_xor(ss, 1);
    ss += __shfl_xor(ss, 2);
    ss += __shfl_xor(ss, 4);
    ss += __shfl_xor(ss, 8);
    if (f15 == 0) sXsq[buf][row] = ss;
    const int slot = s ^ (row & 7);           // R1-family swizzle (verified)
    *reinterpret_cast<f16x4*>(&sX[buf][row * KDIM + slot * 8 + half * 4]) = hv;
  };

  // ---- prologue ----
  float4 rx;
  if (tid < 512) rx = xsrc[tid];              // x tile 0 (oldest vmcnt)

  // centers: f32 -> fp16 LDS (swizzled) + csq, in-block (k1 merged)
  {
    const float4* cf = reinterpret_cast<const float4*>(centers);
    #pragma unroll
    for (int p = 0; p < 8; ++p) {
      const int c = p * 1024 + tid;           // 8-elem chunk id 0..8191
      const int row = c >> 3;                 // 0..1023
      const int s = c & 7;
      const float4 v0 = cf[c * 2];
      const float4 v1 = cf[c * 2 + 1];
      const float v[8] = {v0.x, v0.y, v0.z, v0.w, v1.x, v1.y, v1.z, v1.w};
      f16x8 hv;
      float ss = 0.0f;
      #pragma unroll
      for (int i = 0; i < 8; ++i) {
        hv[i] = (_Float16)v[i];               // RNE
        ss += v[i] * v[i];                    // norms from exact f32
      }
      ss += __shfl_xor(ss, 1);
      ss += __shfl_xor(ss, 2);
      ss += __shfl_xor(ss, 4);
      if (s == 0) sCsq[row] = ss;
      const int slot = s ^ (row & 7);
      *reinterpret_cast<f16x8*>(&sCen[row * KDIM + slot * 8]) = hv;
    }
  }
  if (tid < 512) {
    convert_x(rx, 0);                         // compiler waits counted vmcnt
    rx = xsrc[512 + tid];                     // x tile 1 in flight
  }
  __syncthreads();                            // one-time full staging drain

  const int lane = tid & 63;
  const int wave = tid >> 6;                  // 0..15
  const int wm = wave & 1;                    // 16-row group within sub-tile
  const int wn = wave >> 1;                   // 128-col group (0..7)
  const int l = lane & 15;
  const int g = lane >> 4;                    // k-group 0..3

  // ================= 8 iterations: 32 rows x 1024 cols each =================
  #pragma unroll 1
  for (int jt = 0; jt < NSUB; ++jt) {
    const int b = jt & 1;

    // stage next x sub-tile (dbuf; barrier at prev iter end protects buf b^1)
    if (jt + 1 < NSUB && tid < 512) convert_x(rx, b ^ 1);
    if (jt + 2 < NSUB && tid < 512) rx = xsrc[(jt + 2) * 512 + tid];

    // x fragments (B-operand): lane l <-> x-row, chunk g
    const int xrow = wm * 16 + l;
    f16x8 xh[2];
    #pragma unroll
    for (int ks = 0; ks < 2; ++ks) {
      const int slot = (ks * 4 + g) ^ (l & 7);
      xh[ks] = *reinterpret_cast<const f16x8*>(&sX[b][xrow * KDIM + slot * 8]);
    }
    const float xs = sXsq[b][xrow];

    const size_t rowg = (size_t)mb * RPB + jt * SUB + wm * 16 + l;
    float* orow = out + rowg * (size_t)NTOT + wn * 128;

    // nf-outer: per 16-center group, 2 MFMA -> finish -> store immediately.
    // Stores start after 2 MFMAs and spread across the iteration.
    #pragma unroll
    for (int nf = 0; nf < 8; ++nf) {
      const int crow = wn * 128 + nf * 16 + l;
      f32x4 acc = {};
      #pragma unroll
      for (int ks = 0; ks < 2; ++ks) {
        const int slot = (ks * 4 + g) ^ (l & 7);
        const f16x8 ch = *reinterpret_cast<const f16x8*>(&sCen[crow * KDIM + slot * 8]);
        acc = __builtin_amdgcn_mfma_f32_16x16x32_f16(ch, xh[ks], acc, 0, 0, 0);
      }
      const float4 cs = *reinterpret_cast<const float4*>(&sCsq[wn * 128 + nf * 16 + g * 4]);
      float4 o;
      o.x = __expf(-GAMMA * fmaxf(xs + cs.x - 2.0f * acc[0], 0.0f));
      o.y = __expf(-GAMMA * fmaxf(xs + cs.y - 2.0f * acc[1], 0.0f));
      o.z = __expf(-GAMMA * fmaxf(xs + cs.z - 2.0f * acc[2], 0.0f));
      o.w = __expf(-GAMMA * fmaxf(xs + cs.w - 2.0f * acc[3], 0.0f));
      *reinterpret_cast<float4*>(orow + nf * 16 + g * 4) = o;
    }

    if (jt + 1 < NSUB) {
      asm volatile("s_waitcnt lgkmcnt(0)" ::: "memory");  // ds_writes visible
      __builtin_amdgcn_s_barrier();                       // raw: stores stay in flight
      __builtin_amdgcn_sched_barrier(0);                  // no hoisting across
    }
  }
}

extern "C" void kernel_launch(void* const* d_in, const int* in_sizes, int n_in,
                              void* d_out, int out_size, void* d_ws, size_t ws_size,
                              hipStream_t stream) {
  (void)in_sizes; (void)n_in; (void)d_ws; (void)ws_size; (void)out_size;
  const float* x       = (const float*)d_in[0];
  const float* centers = (const float*)d_in[1];
  float* out = (float*)d_out;
  rbf_fused_kernel<<<MTOT / RPB, 1024, 0, stream>>>(x, centers, out);
}